// Round 1
// baseline (435.241 us; speedup 1.0000x reference)
//
#include <hip/hip_runtime.h>
#include <hip/hip_bf16.h>
#include <stdint.h>

// LSTM cell fused: gates GEMM (bf16 MFMA) + activations + log_softmax.
// B=65536, IN=H=256, K=512 (input|hidden), 4H=1024 gate columns.

#define BH (65536 * 256)

typedef float f32x4 __attribute__((ext_vector_type(4)));
typedef short short8 __attribute__((ext_vector_type(8)));

__device__ __forceinline__ unsigned short f2bf(float f) {
    union { float f; unsigned u; } v; v.f = f;
    unsigned u = v.u;
    return (unsigned short)((u + 0x7fffu + ((u >> 16) & 1u)) >> 16);
}

__device__ __forceinline__ float sigm(float x) { return 1.f / (1.f + __expf(-x)); }
__device__ __forceinline__ float tanh_(float x) { return 1.f - 2.f / (1.f + __expf(2.f * x)); }

// Packs W (8 matrices) into bf16 MFMA-B-fragment order:
//   wpack[Ct][ks][lane][j] = bf16( W[C(Ct,lane&15)][ks*32 + (lane>>4)*8 + j] )
// where column C = hg*256 + gate*64 + h_local (gate-major within each h-group),
// W row r = gate*256 + h, W[r][k] = Wi_gate[h][k] (k<256) else Wh_gate[h][k-256].
// Also bpack[C] = bi[r] + bh[r].
__global__ __launch_bounds__(256) void pack_kernel(
    const float* __restrict__ Wif, const float* __restrict__ Wii,
    const float* __restrict__ Wio, const float* __restrict__ Wig,
    const float* __restrict__ Whf, const float* __restrict__ Whi,
    const float* __restrict__ Who, const float* __restrict__ Whg,
    const float* __restrict__ bif, const float* __restrict__ bii,
    const float* __restrict__ bio, const float* __restrict__ big,
    const float* __restrict__ bhf, const float* __restrict__ bhi,
    const float* __restrict__ bho, const float* __restrict__ bhg,
    unsigned short* __restrict__ wpack, float* __restrict__ bpack)
{
    const int t = blockIdx.x * 256 + threadIdx.x;   // 0..65535 = (Ct, ks, lane)
    const int l  = t & 63;
    const int ks = (t >> 6) & 15;
    const int Ct = t >> 10;                          // 0..63
    const int n  = l & 15;
    const int C  = Ct * 16 + n;
    const int hg = C >> 8;
    const int cl = C & 255;
    const int gate = cl >> 6;
    const int hl = cl & 63;
    const int h  = hg * 64 + hl;
    const float* Wi = (gate == 0) ? Wif : (gate == 1) ? Wii : (gate == 2) ? Wio : Wig;
    const float* Wh = (gate == 0) ? Whf : (gate == 1) ? Whi : (gate == 2) ? Who : Whg;
    const int kbase = ks * 32 + (l >> 4) * 8;

    unsigned int pk[4];
#pragma unroll
    for (int p = 0; p < 4; ++p) {
        int k0 = kbase + p * 2;
        float w0 = (k0 < 256) ? Wi[h * 256 + k0] : Wh[h * 256 + (k0 - 256)];
        float w1 = (k0 + 1 < 256) ? Wi[h * 256 + k0 + 1] : Wh[h * 256 + (k0 + 1 - 256)];
        pk[p] = (unsigned)f2bf(w0) | ((unsigned)f2bf(w1) << 16);
    }
    uint4 out4 = {pk[0], pk[1], pk[2], pk[3]};
    *(uint4*)&wpack[(size_t)t * 8] = out4;

    if (t < 1024) {
        const int C2 = t;
        const int hg2 = C2 >> 8, cl2 = C2 & 255, g2 = cl2 >> 6, hl2 = cl2 & 63;
        const int h2 = hg2 * 64 + hl2;
        const float* bi = (g2 == 0) ? bif : (g2 == 1) ? bii : (g2 == 2) ? bio : big;
        const float* bh = (g2 == 0) ? bhf : (g2 == 1) ? bhi : (g2 == 2) ? bho : bhg;
        bpack[C2] = bi[h2] + bh[h2];
    }
}

// Main fused kernel: block = 32 rows x 1024 gate cols, 8 waves (4 hg x 2 rg),
// each wave 16 rows x 256 cols via mfma_f32_16x16x32_bf16.
__global__ __launch_bounds__(512) void lstm_kernel(
    const float* __restrict__ input, const float* __restrict__ hidden,
    const float* __restrict__ cell,
    const unsigned short* __restrict__ wpack, const float* __restrict__ bpack,
    float* __restrict__ out)
{
    // A-tile in fragment-linear layout: [rg][ks][kg][row16][8] halfwords
    __shared__ unsigned short A_lds[16384];   // 32 KB
    __shared__ float red[2][16][4];           // cross-wave softmax partials

    const int tid = threadIdx.x;
    const int row0 = blockIdx.x * 32;

    // ---- stage X = [input | hidden] rows, f32 -> bf16, into LDS ----
    {
        const int row = tid >> 4;             // 0..31
        const size_t row_g = (size_t)(row0 + row);
        const int rg = row >> 4, r16 = row & 15;
#pragma unroll
        for (int it = 0; it < 8; ++it) {
            const int k4 = (tid & 15) + it * 16;   // 0..127
            const int k = k4 * 4;
            float4 xv;
            if (k < 256) xv = *(const float4*)(input  + row_g * 256 + k);
            else         xv = *(const float4*)(hidden + row_g * 256 + (k - 256));
            const int ks = k >> 5, kk = k & 31, kg = kk >> 3, j0 = kk & 7;
            uint2 w;
            w.x = (unsigned)f2bf(xv.x) | ((unsigned)f2bf(xv.y) << 16);
            w.y = (unsigned)f2bf(xv.z) | ((unsigned)f2bf(xv.w) << 16);
            const int idx = (((rg * 16 + ks) * 4 + kg) * 16 + r16) * 8 + j0;
            *(uint2*)&A_lds[idx] = w;
        }
    }
    __syncthreads();

    const int wid  = tid >> 6;    // 0..7
    const int lane = tid & 63;
    const int hg = wid & 3;       // h-group: 64 h values -> 256 gate cols
    const int rg = wid >> 2;      // row-group: 16 rows

    f32x4 acc[16];
#pragma unroll
    for (int i = 0; i < 16; ++i) acc[i] = (f32x4){0.f, 0.f, 0.f, 0.f};

    const short8* __restrict__ wp = (const short8*)wpack + (size_t)hg * 16384 + lane;
    const unsigned short* abase = A_lds + rg * 16 * 512 + lane * 8;

#pragma unroll 4
    for (int ks = 0; ks < 16; ++ks) {
        short8 a = *(const short8*)(abase + ks * 512);
#pragma unroll
        for (int nt = 0; nt < 16; ++nt) {
            short8 b = wp[(nt * 16 + ks) * 64];
            acc[nt] = __builtin_amdgcn_mfma_f32_16x16x32_bf16(a, b, acc[nt], 0, 0, 0);
        }
    }

    // ---- epilogue: bias, activations, cell update, log_softmax ----
    const int n16 = lane & 15;    // C/D col within tile
    const int lrow = lane >> 4;   // C/D row group (rows lrow*4 + r)

#pragma unroll
    for (int nt = 0; nt < 16; ++nt) {
        const float bv = bpack[hg * 256 + nt * 16 + n16];
        acc[nt][0] += bv; acc[nt][1] += bv; acc[nt][2] += bv; acc[nt][3] += bv;
    }

    float nh[4][4];               // [q][r]
    float s[4] = {0.f, 0.f, 0.f, 0.f};
#pragma unroll
    for (int q = 0; q < 4; ++q) {
        const int h = hg * 64 + q * 16 + n16;
#pragma unroll
        for (int r = 0; r < 4; ++r) {
            const size_t row_g = (size_t)(row0 + rg * 16 + lrow * 4 + r);
            const float fv = sigm(acc[q][r]);
            const float iv = sigm(acc[q + 4][r]);
            const float ov = sigm(acc[q + 8][r]);
            const float gv = tanh_(acc[q + 12][r]);
            const float cv = cell[row_g * 256 + h];
            const float nc = fv * cv + iv * gv;
            const float nhv = ov * tanh_(nc);
            out[(size_t)2 * BH + row_g * 256 + h] = nc;
            out[(size_t)BH + row_g * 256 + h] = nhv;
            nh[q][r] = nhv;
            s[r] += __expf(nhv);  // nh in (-1,1): no max-subtraction needed
        }
    }
    // reduce sum over the 16 lanes sharing each row
#pragma unroll
    for (int m = 1; m < 16; m <<= 1) {
#pragma unroll
        for (int r = 0; r < 4; ++r) s[r] += __shfl_xor(s[r], m);
    }
    if (n16 == 0) {
#pragma unroll
        for (int r = 0; r < 4; ++r) red[rg][lrow * 4 + r][hg] = s[r];
    }
    __syncthreads();
    float lz[4];
#pragma unroll
    for (int r = 0; r < 4; ++r) {
        const int m = lrow * 4 + r;
        lz[r] = __logf(red[rg][m][0] + red[rg][m][1] + red[rg][m][2] + red[rg][m][3]);
    }
#pragma unroll
    for (int q = 0; q < 4; ++q) {
        const int h = hg * 64 + q * 16 + n16;
#pragma unroll
        for (int r = 0; r < 4; ++r) {
            const size_t row_g = (size_t)(row0 + rg * 16 + lrow * 4 + r);
            out[row_g * 256 + h] = nh[q][r] - lz[r];
        }
    }
}

extern "C" void kernel_launch(void* const* d_in, const int* in_sizes, int n_in,
                              void* d_out, int out_size, void* d_ws, size_t ws_size,
                              hipStream_t stream)
{
    const float* input  = (const float*)d_in[0];
    const float* hidden = (const float*)d_in[1];
    const float* cell   = (const float*)d_in[2];
    const float* Wif = (const float*)d_in[3];  const float* bif = (const float*)d_in[4];
    const float* Wii = (const float*)d_in[5];  const float* bii = (const float*)d_in[6];
    const float* Wio = (const float*)d_in[7];  const float* bio = (const float*)d_in[8];
    const float* Wig = (const float*)d_in[9];  const float* big = (const float*)d_in[10];
    const float* Whf = (const float*)d_in[11]; const float* bhf = (const float*)d_in[12];
    const float* Whi = (const float*)d_in[13]; const float* bhi = (const float*)d_in[14];
    const float* Who = (const float*)d_in[15]; const float* bho = (const float*)d_in[16];
    const float* Whg = (const float*)d_in[17]; const float* bhg = (const float*)d_in[18];

    unsigned short* wpack = (unsigned short*)d_ws;                      // 1 MB
    float* bpack = (float*)((char*)d_ws + (size_t)64 * 16 * 64 * 8 * 2); // 4 KB

    hipLaunchKernelGGL(pack_kernel, dim3(256), dim3(256), 0, stream,
        Wif, Wii, Wio, Wig, Whf, Whi, Who, Whg,
        bif, bii, bio, big, bhf, bhi, bho, bhg, wpack, bpack);

    hipLaunchKernelGGL(lstm_kernel, dim3(2048), dim3(512), 0, stream,
        input, hidden, cell, wpack, bpack, (float*)d_out);
}

// Round 2
// 167.988 us; speedup vs baseline: 2.5909x; 2.5909x over previous
//
#include <hip/hip_runtime.h>
#include <hip/hip_bf16.h>
#include <stdint.h>

// LSTM cell fused, two-kernel version:
//   pack:  weights -> bf16 MFMA-fragment layout (1 MB), bias -> packed cols
//   K1:    gates GEMM (128x256 tile, BK=32, dbuf LDS, global_load_lds for B,
//          reg-staged f32->bf16 for A) + gate activations + cell update.
//          Writes new_cell, new_hidden to d_out.
//   K2:    per-row log_softmax finalize (reads nh, writes output 0).
// B=65536, IN=H=256, K=512, 4H=1024 gate cols.

#define BH 16777216  // 65536*256

typedef float f32x4 __attribute__((ext_vector_type(4)));
typedef short short8 __attribute__((ext_vector_type(8)));

__device__ __forceinline__ unsigned short f2bf(float f) {
    union { float f; unsigned u; } v; v.f = f;
    unsigned u = v.u;
    return (unsigned short)((u + 0x7fffu + ((u >> 16) & 1u)) >> 16);
}

__device__ __forceinline__ unsigned pack2bf(float a, float b) {
    __hip_bfloat162 h = __float22bfloat162_rn(make_float2(a, b));
    union { __hip_bfloat162 h; unsigned u; } v; v.h = h;
    return v.u;  // emits v_cvt_pk_bf16_f32
}

__device__ __forceinline__ float sigm(float x) { return 1.f / (1.f + __expf(-x)); }
__device__ __forceinline__ float tanh_(float x) { return 1.f - 2.f / (1.f + __expf(2.f * x)); }

__device__ __forceinline__ void glds16(const unsigned short* g, const unsigned short* l) {
    __builtin_amdgcn_global_load_lds(
        (const __attribute__((address_space(1))) unsigned int*)(uintptr_t)g,
        (__attribute__((address_space(3))) unsigned int*)(unsigned int)(uintptr_t)l,
        16, 0, 0);
}

// ---- pack: wpack[hg][step(16)][Nt(16)][lane(64)][j(8)] bf16 ----
// packed col cp = hg*256 + Nt*16 + n16 ; Nt = wc*4 + gate ; h = hg*64+wc*16+n16
// value = W[gate*256+h][k], k = step*32 + (lane>>4)*8 + j
__global__ __launch_bounds__(256) void pack_kernel(
    const float* __restrict__ Wif, const float* __restrict__ Wii,
    const float* __restrict__ Wio, const float* __restrict__ Wig,
    const float* __restrict__ Whf, const float* __restrict__ Whi,
    const float* __restrict__ Who, const float* __restrict__ Whg,
    const float* __restrict__ bif, const float* __restrict__ bii,
    const float* __restrict__ bio, const float* __restrict__ big,
    const float* __restrict__ bhf, const float* __restrict__ bhi,
    const float* __restrict__ bho, const float* __restrict__ bhg,
    unsigned short* __restrict__ wpack, float* __restrict__ bpack)
{
    const int t = blockIdx.x * 256 + threadIdx.x;   // 0..65535
    const int n16  = t & 15;
    const int kg   = (t >> 4) & 3;
    const int Nt   = (t >> 6) & 15;
    const int step = (t >> 10) & 15;
    const int hg   = t >> 14;
    const int gate = Nt & 3;
    const int wc   = Nt >> 2;
    const int h    = hg * 64 + wc * 16 + n16;       // 0..255
    const int k0   = step * 32 + kg * 8;            // 0..511, 8-aligned

    const float* Wi = (gate == 0) ? Wif : (gate == 1) ? Wii : (gate == 2) ? Wio : Wig;
    const float* Wh = (gate == 0) ? Whf : (gate == 1) ? Whi : (gate == 2) ? Who : Whg;
    const float* src = (k0 < 256) ? (Wi + h * 256 + k0) : (Wh + h * 256 + (k0 - 256));

    unsigned pk[4];
#pragma unroll
    for (int p = 0; p < 4; ++p)
        pk[p] = (unsigned)f2bf(src[p * 2]) | ((unsigned)f2bf(src[p * 2 + 1]) << 16);
    uint4 o4 = {pk[0], pk[1], pk[2], pk[3]};
    *(uint4*)&wpack[(size_t)t * 8] = o4;

    if (t < 1024) {
        const int cp = t;
        const int n2 = cp & 15, Nt2 = (cp >> 4) & 15, hg2 = cp >> 8;
        const int g2 = Nt2 & 3, wc2 = Nt2 >> 2;
        const int h2 = hg2 * 64 + wc2 * 16 + n2;
        const float* bi = (g2 == 0) ? bif : (g2 == 1) ? bii : (g2 == 2) ? bio : big;
        const float* bh = (g2 == 0) ? bhf : (g2 == 1) ? bhi : (g2 == 2) ? bho : bhg;
        bpack[cp] = bi[h2] + bh[h2];
    }
}

// ---- K1: GEMM + gates. grid 2048 = 512 rowTiles x 4 hg, block 512 (8 waves) ----
__global__ __launch_bounds__(512, 4) void lstm_gemm_kernel(
    const float* __restrict__ input, const float* __restrict__ hidden,
    const float* __restrict__ cell,
    const unsigned short* __restrict__ wpack, const float* __restrict__ bpack,
    float* __restrict__ out)
{
    // per buffer: A frags 4096 hw (8KB) + B frags 8192 hw (16KB)
    __shared__ unsigned short buf[2][12288];

    // XCD-bijective swizzle (2048 % 8 == 0): quad of hg-blocks stays on one XCD
    const int swz = (blockIdx.x & 7) * 256 + (blockIdx.x >> 3);
    const int hg  = swz & 3;
    const int row0 = (swz >> 2) * 128;

    const int tid = threadIdx.x;
    const int w = tid >> 6, l = tid & 63;
    const int wr = w >> 2, wc = w & 3;
    const int srow = tid >> 2;   // 0..127 staging row
    const int skc  = tid & 3;    // k-chunk (8 floats)

    const unsigned short* wsrc = wpack + (((size_t)hg * 16) << 13) + w * 1024 + l * 8;

    // ---- prologue: stage step 0 into buf[0] ----
    {
        glds16(wsrc, &buf[0][4096 + w * 1024]);
        glds16(wsrc + 512, &buf[0][4096 + w * 1024 + 512]);
        const float* asrc = input + (size_t)(row0 + srow) * 256 + skc * 8;
        float4 x0 = *(const float4*)asrc;
        float4 x1 = *(const float4*)(asrc + 4);
        uint4 o; o.x = pack2bf(x0.x, x0.y); o.y = pack2bf(x0.z, x0.w);
        o.z = pack2bf(x1.x, x1.y); o.w = pack2bf(x1.z, x1.w);
        *(uint4*)&buf[0][((srow >> 4) * 64 + skc * 16 + (srow & 15)) << 3] = o;
    }
    __syncthreads();

    f32x4 acc[4][4] = {};

#pragma unroll 2
    for (int step = 0; step < 16; ++step) {
        const int cb = step & 1, nb = cb ^ 1;
        float4 x0, x1;
        if (step < 15) {
            const unsigned short* ws = wsrc + ((size_t)(step + 1) << 13);
            glds16(ws, &buf[nb][4096 + w * 1024]);
            glds16(ws + 512, &buf[nb][4096 + w * 1024 + 512]);
            const int k0 = (step + 1) * 32 + skc * 8;
            const float* asrc = (k0 < 256)
                ? input  + (size_t)(row0 + srow) * 256 + k0
                : hidden + (size_t)(row0 + srow) * 256 + (k0 - 256);
            x0 = *(const float4*)asrc;
            x1 = *(const float4*)(asrc + 4);
        }
        short8 Af[4], Bf[4];
#pragma unroll
        for (int m = 0; m < 4; ++m)
            Af[m] = *(const short8*)&buf[cb][((wr * 4 + m) * 64 + l) << 3];
#pragma unroll
        for (int n = 0; n < 4; ++n)
            Bf[n] = *(const short8*)&buf[cb][4096 + (((wc * 4 + n) * 64 + l) << 3)];
#pragma unroll
        for (int m = 0; m < 4; ++m)
#pragma unroll
            for (int n = 0; n < 4; ++n)
                acc[m][n] = __builtin_amdgcn_mfma_f32_16x16x32_bf16(Af[m], Bf[n], acc[m][n], 0, 0, 0);
        if (step < 15) {
            uint4 o; o.x = pack2bf(x0.x, x0.y); o.y = pack2bf(x0.z, x0.w);
            o.z = pack2bf(x1.x, x1.y); o.w = pack2bf(x1.z, x1.w);
            *(uint4*)&buf[nb][((srow >> 4) * 64 + skc * 16 + (srow & 15)) << 3] = o;
        }
        __syncthreads();
    }

    // ---- epilogue: bias + activations + cell update ----
    const int n16 = l & 15;
    const int lrow = l >> 4;
    const int hcol = hg * 64 + wc * 16 + n16;
    float bias[4];
#pragma unroll
    for (int n = 0; n < 4; ++n)
        bias[n] = bpack[hg * 256 + wc * 64 + n * 16 + n16];

#pragma unroll
    for (int m = 0; m < 4; ++m) {
#pragma unroll
        for (int rr = 0; rr < 4; ++rr) {
            const size_t rg_ = (size_t)row0 + wr * 64 + m * 16 + lrow * 4 + rr;
            const float fv = sigm(acc[m][0][rr] + bias[0]);
            const float iv = sigm(acc[m][1][rr] + bias[1]);
            const float ov = sigm(acc[m][2][rr] + bias[2]);
            const float gv = tanh_(acc[m][3][rr] + bias[3]);
            const float cv = cell[rg_ * 256 + hcol];
            const float nc = fv * cv + iv * gv;
            const float nhv = ov * tanh_(nc);
            out[(size_t)2 * BH + rg_ * 256 + hcol] = nc;
            out[(size_t)BH + rg_ * 256 + hcol] = nhv;
        }
    }
}

// ---- K2: log_softmax finalize. out[0..BH) = nh - log(sum(exp(nh))) ----
__global__ __launch_bounds__(256) void softmax_kernel(
    const float* __restrict__ nh, float* __restrict__ outp)
{
    const int w = threadIdx.x >> 6, l = threadIdx.x & 63;
#pragma unroll 1
    for (int it = 0; it < 8; ++it) {
        const size_t row = (size_t)it * 8192 + blockIdx.x * 4 + w;
        float4 v = *(const float4*)(nh + row * 256 + l * 4);
        float s = __expf(v.x) + __expf(v.y) + __expf(v.z) + __expf(v.w);
#pragma unroll
        for (int m = 1; m < 64; m <<= 1) s += __shfl_xor(s, m);
        const float lz = __logf(s);
        float4 o = {v.x - lz, v.y - lz, v.z - lz, v.w - lz};
        *(float4*)(outp + row * 256 + l * 4) = o;
    }
}

extern "C" void kernel_launch(void* const* d_in, const int* in_sizes, int n_in,
                              void* d_out, int out_size, void* d_ws, size_t ws_size,
                              hipStream_t stream)
{
    const float* input  = (const float*)d_in[0];
    const float* hidden = (const float*)d_in[1];
    const float* cell   = (const float*)d_in[2];
    const float* Wif = (const float*)d_in[3];  const float* bif = (const float*)d_in[4];
    const float* Wii = (const float*)d_in[5];  const float* bii = (const float*)d_in[6];
    const float* Wio = (const float*)d_in[7];  const float* bio = (const float*)d_in[8];
    const float* Wig = (const float*)d_in[9];  const float* big = (const float*)d_in[10];
    const float* Whf = (const float*)d_in[11]; const float* bhf = (const float*)d_in[12];
    const float* Whi = (const float*)d_in[13]; const float* bhi = (const float*)d_in[14];
    const float* Who = (const float*)d_in[15]; const float* bho = (const float*)d_in[16];
    const float* Whg = (const float*)d_in[17]; const float* bhg = (const float*)d_in[18];

    unsigned short* wpack = (unsigned short*)d_ws;                        // 1 MB
    float* bpack = (float*)((char*)d_ws + (size_t)1024 * 512 * 2);        // 4 KB

    hipLaunchKernelGGL(pack_kernel, dim3(256), dim3(256), 0, stream,
        Wif, Wii, Wio, Wig, Whf, Whi, Who, Whg,
        bif, bii, bio, big, bhf, bhi, bho, bhg, wpack, bpack);

    float* out = (float*)d_out;
    hipLaunchKernelGGL(lstm_gemm_kernel, dim3(2048), dim3(512), 0, stream,
        input, hidden, cell, wpack, bpack, out);

    hipLaunchKernelGGL(softmax_kernel, dim3(2048), dim3(256), 0, stream,
        out + (size_t)BH, out);
}